// Round 10
// baseline (17990.947 us; speedup 1.0000x reference)
//
#include <hip/hip_runtime.h>
#include <math.h>
#include <stdint.h>

namespace {
constexpr int INN   = 512;           // visible rows: act[:512] == x always
constexpr int LAY   = 2048;
constexpr int DYN   = LAY - INN;     // 1536 dynamic elements act[512..2048)
constexpr int NITER = 512;
constexpr int NCAND = 512;           // candidate blocks launched
constexpr int TPB   = 512;           // 8 waves
constexpr int WVS   = TPB / 64;      // 8
constexpr int RPW   = 6;             // rows per wave (R4-proven per-thread shape)
constexpr int RPB   = WVS * RPW;     // 48 rows per worker block
constexpr int NWRK  = DYN / RPB;     // 32 workers (1 per CU of one XCD)
constexpr int KC    = DYN / 64;      // 24 dynamic k-chunks per lane
constexpr int KX    = INN / 64;      // 8 x-col k-chunks (precomputed)
constexpr int EPT   = DYN / TPB;     // 3 polled elements per thread
constexpr int FASTBUDGET = 2048;     // sc0 poll passes before sticky-UC fallback
constexpr float EPS = 1e-12f;

__device__ __forceinline__ uint64_t pack(float v, uint32_t tag) {
  union { float f; uint32_t u; } c; c.f = v;
  return (uint64_t)c.u | ((uint64_t)tag << 32);
}
__device__ __forceinline__ float val_of(uint64_t p) {
  union { uint32_t u; float f; } c; c.u = (uint32_t)p; return c.f;
}
// Proven agent-UC medium (R2/R3/R4/R7: absmax 0.0). Correctness anchor.
__device__ __forceinline__ void ag_store64(uint64_t* p, uint64_t v) {
  __hip_atomic_store(p, v, __ATOMIC_RELAXED, __HIP_MEMORY_SCOPE_AGENT);
}
__device__ __forceinline__ uint64_t ag_load64(const uint64_t* p) {
  return __hip_atomic_load(p, __ATOMIC_RELAXED, __HIP_MEMORY_SCOPE_AGENT);
}
__device__ __forceinline__ uint32_t ag_loadu(const uint32_t* p) {
  return __hip_atomic_load(p, __ATOMIC_RELAXED, __HIP_MEMORY_SCOPE_AGENT);
}
// Plain (cached, write-through to local L2) store; workgroup scope = plain
// global_store, compiler-ordered. Single 8B inst -> value+tag never tear.
__device__ __forceinline__ void wg_store64(uint64_t* p, uint64_t v) {
  __hip_atomic_store(p, v, __ATOMIC_RELAXED, __HIP_MEMORY_SCOPE_WORKGROUP);
}
// Fast poll: sc0 loads bypass L1, are served by the (shared, per-XCD) L2 —
// sees same-XCD write-through stores at L2 latency.
__device__ __forceinline__ void poll3_sc0(const uint64_t* p,
                                          uint64_t& q0, uint64_t& q1, uint64_t& q2) {
  asm volatile(
      "global_load_dwordx2 %0, %3, off sc0\n\t"
      "global_load_dwordx2 %1, %3, off offset:8 sc0\n\t"
      "global_load_dwordx2 %2, %3, off offset:16 sc0\n\t"
      "s_waitcnt vmcnt(0)"
      : "=&v"(q0), "=&v"(q1), "=&v"(q2) : "v"(p) : "memory");
}

// Persistent, all 512 iterations in one launch; 32 worker blocks co-located
// on ONE XCD exchange through its shared L2 (fast tier) with the proven
// agent-UC anchor as unconditional fallback (slow tier). Tagged ping-pong
// protocol identical to R4 (absmax 0.0): a block stores tag t+1 only after
// block-wide consumption of tag t, so tag t+2 stores (clobbering t) imply
// every block consumed t. Dual-publish keeps BOTH tiers valid under any
// block placement; per-thread sticky fallback has no give-up valve -> the
// worst failure mode is R4-class speed, never a wrong/empty output.
__global__ __launch_bounds__(TPB, 1) void bm_xcd(
    const float* __restrict__ x, const float* __restrict__ W,
    uint64_t* __restrict__ ws, uint32_t* __restrict__ ctl,
    float* __restrict__ out) {
  __shared__ float s_act[DYN];
  __shared__ float s_red[WVS];
  __shared__ int s_tk;
  const int tid = threadIdx.x;
  const int wv  = tid >> 6;
  const int ln  = tid & 63;

  // ---- election: group blocks by physical XCD; first group to reach 32
  // arrivals is chosen; its first 32 arrivals become workers. Guaranteed to
  // resolve: <=256 blocks hold all CUs, so some XCD accrues >=32 arrivals.
  // Needs only "equal iff same XCD" from XCC_ID; degenerate values degrade
  // to scattered workers (slow tier), never to deadlock or wrong output.
  if (tid == 0) {
    uint32_t xcc;
    asm volatile("s_getreg_b32 %0, hwreg(HW_REG_XCC_ID)" : "=s"(xcc));
    xcc &= 7u;
    const uint32_t rank = atomicAdd(&ctl[xcc], 1u);      // device-scope
    if (rank == NWRK - 1) atomicCAS(&ctl[8], 0u, xcc + 1u);
    int tk = -1;
    if (rank < NWRK) {
      uint32_t chosen;
      while ((chosen = ag_loadu(&ctl[8])) == 0u) {}      // resolves (see above)
      if (chosen == xcc + 1u) tk = (int)rank;
    }
    s_tk = tk;
  }
  __syncthreads();
  const int tk = s_tk;
  if (tk < 0) return;

  uint64_t* const fp0 = ws;             // plain (L2) medium, parity 0
  uint64_t* const fp1 = ws + DYN;       // plain, parity 1
  uint64_t* const ap0 = ws + 2 * DYN;   // anchor (agent-UC/MALL), parity 0
  uint64_t* const ap1 = ws + 3 * DYN;   // anchor, parity 1

  const int r0 = INN + tk * RPB + wv * RPW;   // this wave's 6 rows
  const int e0 = EPT * tid;                   // my 3 polled elements

  // ---- one-time: W[r,512:2048] into registers/AGPRs ----
  float w[RPW][KC];
  const float* __restrict__ Wr = W + (size_t)r0 * LAY;
#pragma unroll
  for (int r = 0; r < RPW; ++r)
#pragma unroll
    for (int i = 0; i < KC; ++i)
      w[r][i] = Wr[(size_t)r * LAY + INN + ln + 64 * i];

  // ---- one-time: c_r = W[r,:512]@x (fully reduced; added AFTER lane-reduce) ----
  float c[RPW];
  {
    float xv[KX];
#pragma unroll
    for (int i = 0; i < KX; ++i) xv[i] = x[ln + 64 * i];
#pragma unroll
    for (int r = 0; r < RPW; ++r) {
      float cc = 0.f;
#pragma unroll
      for (int i = 0; i < KX; ++i)
        cc = fmaf(Wr[(size_t)r * LAY + ln + 64 * i], xv[i], cc);
#pragma unroll
      for (int o = 1; o < 64; o <<= 1) cc += __shfl_xor(cc, o, 64);
      c[r] = cc;
    }
  }

  // ---- bootstrap: act(1) = relu(c_r), tag 1 -> parity 1, both media ----
  if (ln == 0) {
#pragma unroll
    for (int r = 0; r < RPW; ++r) {
      const uint64_t v = pack(fmaxf(c[r], 0.f), 1u);
      wg_store64(&fp1[r0 - INN + r], v);
      ag_store64(&ap1[r0 - INN + r], v);
    }
  }

  bool fm = true;                        // per-thread sticky fast-mode flag
  float myv[EPT];
  float inv = 0.f;

  for (int t = 1;; ++t) {
    if (t == NITER && tk != 0) return;   // non-0 workers already stored 512

    // ---- poll act(t): fast tier (sc0/L2) with budget, sticky-UC fallback ----
    const uint64_t* fb = ((t & 1) ? fp1 : fp0) + e0;
    const uint64_t* ab = ((t & 1) ? ap1 : ap0) + e0;
    uint64_t q0, q1, q2;
    int pass = 0;
    for (;;) {
      if (fm) {
        poll3_sc0(fb, q0, q1, q2);
      } else {
        q0 = ag_load64(ab); q1 = ag_load64(ab + 1); q2 = ag_load64(ab + 2);
      }
      if ((uint32_t)(q0 >> 32) == (uint32_t)t &&
          (uint32_t)(q1 >> 32) == (uint32_t)t &&
          (uint32_t)(q2 >> 32) == (uint32_t)t) break;
      if (fm && ++pass > FASTBUDGET) fm = false;   // permanent, per-thread
    }

    // ---- stage to LDS + hidden sum-of-squares (dyn element >= 512) ----
    myv[0] = val_of(q0); myv[1] = val_of(q1); myv[2] = val_of(q2);
    float ss = 0.f;
#pragma unroll
    for (int j = 0; j < EPT; ++j) {
      s_act[e0 + j] = myv[j];
      if (e0 + j >= 512) ss = fmaf(myv[j], myv[j], ss);
    }
#pragma unroll
    for (int o = 1; o < 64; o <<= 1) ss += __shfl_xor(ss, o, 64);
    if (ln == 0) s_red[wv] = ss;
    __syncthreads();                     // (A) consumption complete block-wide
    float sst = 0.f;
#pragma unroll
    for (int i = 0; i < WVS; ++i) sst += s_red[i];
    inv = 1.0f / fmaxf(sqrtf(sst), EPS);

    if (t == NITER) break;               // only tk 0 reaches

    // ---- matvec: y = relu(c + W[:,y-region]@a + inv * W[:,hidden]@h) ----
    float aa[RPW], bb[RPW];
#pragma unroll
    for (int r = 0; r < RPW; ++r) { aa[r] = 0.f; bb[r] = 0.f; }
#pragma unroll
    for (int i = 0; i < 8; ++i) {        // dyn cols [0,512): y-region
      const float a = s_act[ln + 64 * i];
#pragma unroll
      for (int r = 0; r < RPW; ++r) aa[r] = fmaf(w[r][i], a, aa[r]);
    }
#pragma unroll
    for (int i = 8; i < KC; ++i) {       // dyn cols [512,1536): hidden
      const float a = s_act[ln + 64 * i];
#pragma unroll
      for (int r = 0; r < RPW; ++r) bb[r] = fmaf(w[r][i], a, bb[r]);
    }
    float y[RPW];
#pragma unroll
    for (int r = 0; r < RPW; ++r) y[r] = fmaf(inv, bb[r], aa[r]);
#pragma unroll
    for (int o = 1; o < 64; o <<= 1) {
#pragma unroll
      for (int r = 0; r < RPW; ++r) y[r] += __shfl_xor(y[r], o, 64);
    }
#pragma unroll
    for (int r = 0; r < RPW; ++r) y[r] = fmaxf(y[r] + c[r], 0.f);  // c AFTER reduce
    __syncthreads();                     // (B) WAR: LDS reads done before restage

    // ---- dual-publish act(t+1), tag t+1 ----
    if (ln == 0) {
      uint64_t* fw = ((t + 1) & 1) ? fp1 : fp0;
      uint64_t* aw = ((t + 1) & 1) ? ap1 : ap0;
      const uint32_t nt = (uint32_t)(t + 1);
#pragma unroll
      for (int r = 0; r < RPW; ++r) {
        const uint64_t v = pack(y[r], nt);
        wg_store64(&fw[r0 - INN + r], v);   // fast tier: lands in shared L2
        ag_store64(&aw[r0 - INN + r], v);   // anchor tier: lands at MALL
      }
    }
  }

  // ---- worker 0: final output (hidden part normalized) ----
  out[tid] = x[tid];                     // TPB == INN == 512
#pragma unroll
  for (int j = 0; j < EPT; ++j) {
    const int e = e0 + j;
    out[INN + e] = (e < 512) ? myv[j] : myv[j] * inv;
  }
}
} // namespace

extern "C" void kernel_launch(void* const* d_in, const int* in_sizes, int n_in,
                              void* d_out, int out_size, void* d_ws, size_t ws_size,
                              hipStream_t stream) {
  const float* x = (const float*)d_in[0];
  // d_in[1] (y) only enters the reference as zeros_like -> unused.
  const float* W = (const float*)d_in[2];
  float* out = (float*)d_out;

  uint64_t* ws  = (uint64_t*)d_ws;
  uint32_t* ctl = (uint32_t*)((char*)d_ws + (size_t)4 * DYN * sizeof(uint64_t));

  // Zero tags (tag 0 matches no t in 1..512) in both media + election state.
  // Required every call: fresh-alloc garbage on call 1, stale tags on replays.
  hipMemsetAsync(d_ws, 0, (size_t)4 * DYN * sizeof(uint64_t) + 64, stream);

  bm_xcd<<<dim3(NCAND), dim3(TPB), 0, stream>>>(x, W, ws, ctl, out);
}

// Round 11
// 1334.956 us; speedup vs baseline: 13.4768x; 13.4768x over previous
//
#include <hip/hip_runtime.h>
#include <math.h>
#include <stdint.h>

namespace {
constexpr int INN   = 512;          // visible rows: act[:512] == x always
constexpr int LAY   = 2048;
constexpr int DYN   = LAY - INN;    // 1536 dynamic elements act[512..2048)
constexpr int NITER = 512;
constexpr int NBLK  = 64;
constexpr int TPB   = 256;          // 4 waves
constexpr int WVS   = TPB / 64;     // 4
constexpr int RPW   = 6;            // rows per wave
constexpr int RPB   = WVS * RPW;    // 24 rows/block; 64*24 = 1536
constexpr int KC    = DYN / 64;     // 24 dynamic k-chunks per lane
constexpr int KX    = INN / 64;     // 8 x-col k-chunks (precomputed)
constexpr int EPT   = DYN / TPB;    // 6 polled elements per thread
constexpr float EPS = 1e-12f;

__device__ __forceinline__ uint64_t packtag(float v, uint32_t tag) {
  union { float f; uint32_t u; } c; c.f = v;
  return (uint64_t)c.u | ((uint64_t)tag << 32);
}
__device__ __forceinline__ float val_of(uint64_t p) {
  union { uint32_t u; float f; } c; c.u = (uint32_t)p; return c.f;
}
// Proven medium (R2/R3/R4/R7/R8/R9 all absmax 0.0): agent-scope UC ops,
// served at MALL, cross-XCD coherent, no fences needed.
__device__ __forceinline__ void ag_store64(uint64_t* p, uint64_t v) {
  __hip_atomic_store(p, v, __ATOMIC_RELAXED, __HIP_MEMORY_SCOPE_AGENT);
}
__device__ __forceinline__ uint64_t ag_load64(const uint64_t* p) {
  return __hip_atomic_load(p, __ATOMIC_RELAXED, __HIP_MEMORY_SCOPE_AGENT);
}

// R4 champion restored (1826 us, absmax 0.0), one tweak: producer stores are
// spread across lanes 0..5 (one row-store per lane) instead of 6 serialized
// stores from lane 0 — overlaps store issue + MALL ACK across lanes, taking
// ~1 RTT off the per-iteration critical path. Protocol otherwise identical:
// tagged (value,iter) 8-byte words; a block stores tag t+1 only after
// block-wide consumption of tag t (__syncthreads between poll and store), so
// tag t+2 stores (which clobber t) imply every block consumed t.
__global__ __launch_bounds__(TPB) void bm_tag(
    const float* __restrict__ x, const float* __restrict__ W,
    uint64_t* __restrict__ buf0, uint64_t* __restrict__ buf1,
    float* __restrict__ out) {
  __shared__ float s_act[DYN];
  __shared__ float s_red[WVS];
  const int tid = threadIdx.x;
  const int wv  = tid >> 6;
  const int ln  = tid & 63;
  const int blk = blockIdx.x;
  const int r0  = INN + blk * RPB + wv * RPW;   // this wave's 6 rows

  // ---- one-time: W[r,512:2048] into registers (6x24 = 144 VGPR) ----
  float w[RPW][KC];
  const float* __restrict__ Wr = W + (size_t)r0 * LAY;
#pragma unroll
  for (int r = 0; r < RPW; ++r)
#pragma unroll
    for (int i = 0; i < KC; ++i)
      w[r][i] = Wr[(size_t)r * LAY + INN + ln + 64 * i];

  // ---- one-time: c_r = W[r,:512]@x (fully reduced; added AFTER lane-reduce) ----
  float c[RPW];
  {
    float xv[KX];
#pragma unroll
    for (int i = 0; i < KX; ++i) xv[i] = x[ln + 64 * i];
#pragma unroll
    for (int r = 0; r < RPW; ++r) {
      float cc = 0.f;
#pragma unroll
      for (int i = 0; i < KX; ++i)
        cc = fmaf(Wr[(size_t)r * LAY + ln + 64 * i], xv[i], cc);
#pragma unroll
      for (int o = 1; o < 64; o <<= 1) cc += __shfl_xor(cc, o, 64);
      c[r] = cc;
    }
  }

  // ---- bootstrap: act(1) = relu(c_r), tag 1 -> buf1; lane r stores row r ----
  {
    float cv = c[0];                      // compile-time-indexed select (no scratch)
    cv = (ln == 1) ? c[1] : cv;
    cv = (ln == 2) ? c[2] : cv;
    cv = (ln == 3) ? c[3] : cv;
    cv = (ln == 4) ? c[4] : cv;
    cv = (ln == 5) ? c[5] : cv;
    if (ln < RPW)
      ag_store64(&buf1[r0 - INN + ln], packtag(fmaxf(cv, 0.f), 1u));
  }

  float myv[EPT];
  float inv = 0.f;
  for (int t = 1;; ++t) {
    if (t == NITER && blk != 0) return;   // non-0 blocks already stored tag 512
    uint64_t* rb = (t & 1) ? buf1 : buf0;

    // ---- poll act(t): batched reload of all 6 tagged words per pass ----
    uint64_t pv[EPT];
    for (;;) {
      bool ok = true;
#pragma unroll
      for (int j = 0; j < EPT; ++j)
        pv[j] = ag_load64(&rb[tid + TPB * j]);
#pragma unroll
      for (int j = 0; j < EPT; ++j)
        ok &= ((uint32_t)(pv[j] >> 32) == (uint32_t)t);
      if (ok) break;
    }

    // ---- stage to LDS + sum-of-squares of hidden part (j>=2 <=> e>=512) ----
    float ss = 0.f;
#pragma unroll
    for (int j = 0; j < EPT; ++j) {
      const float v = val_of(pv[j]);
      myv[j] = v;
      s_act[tid + TPB * j] = v;
      if (j >= 2) ss = fmaf(v, v, ss);
    }
#pragma unroll
    for (int o = 1; o < 64; o <<= 1) ss += __shfl_xor(ss, o, 64);
    if (ln == 0) s_red[wv] = ss;
    __syncthreads();                      // poll consumed block-wide; LDS ready
    inv = 1.0f / fmaxf(sqrtf(s_red[0] + s_red[1] + s_red[2] + s_red[3]), EPS);

    if (t == NITER) break;                // only blk 0 reaches

    // ---- matvec: y = relu(c + W[:,y-region]@a + inv * W[:,hidden]@h) ----
    float aa[RPW], bb[RPW];
#pragma unroll
    for (int r = 0; r < RPW; ++r) { aa[r] = 0.f; bb[r] = 0.f; }
#pragma unroll
    for (int i = 0; i < 8; ++i) {         // dyn cols [0,512): y-region
      const float a = s_act[ln + 64 * i];
#pragma unroll
      for (int r = 0; r < RPW; ++r) aa[r] = fmaf(w[r][i], a, aa[r]);
    }
#pragma unroll
    for (int i = 8; i < KC; ++i) {        // dyn cols [512,1536): hidden
      const float a = s_act[ln + 64 * i];
#pragma unroll
      for (int r = 0; r < RPW; ++r) bb[r] = fmaf(w[r][i], a, bb[r]);
    }
    float y[RPW];
#pragma unroll
    for (int r = 0; r < RPW; ++r) y[r] = fmaf(inv, bb[r], aa[r]);
#pragma unroll
    for (int o = 1; o < 64; o <<= 1) {
#pragma unroll
      for (int r = 0; r < RPW; ++r) y[r] += __shfl_xor(y[r], o, 64);
    }
#pragma unroll
    for (int r = 0; r < RPW; ++r) y[r] = fmaxf(y[r] + c[r], 0.f);  // c AFTER reduce
    __syncthreads();                      // WAR: LDS reads done before restage

    // ---- publish act(t+1): lane r stores row r (issue+ACK overlap) ----
    {
      float yv = y[0];                    // compile-time-indexed select
      yv = (ln == 1) ? y[1] : yv;
      yv = (ln == 2) ? y[2] : yv;
      yv = (ln == 3) ? y[3] : yv;
      yv = (ln == 4) ? y[4] : yv;
      yv = (ln == 5) ? y[5] : yv;
      if (ln < RPW) {
        uint64_t* wbuf = ((t + 1) & 1) ? buf1 : buf0;
        ag_store64(&wbuf[r0 - INN + ln], packtag(yv, (uint32_t)(t + 1)));
      }
    }
  }

  // ---- blk 0: final output (hidden part normalized) ----
  out[tid]       = x[tid];
  out[tid + TPB] = x[tid + TPB];
#pragma unroll
  for (int j = 0; j < EPT; ++j)
    out[INN + tid + TPB * j] = (j < 2) ? myv[j] : myv[j] * inv;
}
} // namespace

extern "C" void kernel_launch(void* const* d_in, const int* in_sizes, int n_in,
                              void* d_out, int out_size, void* d_ws, size_t ws_size,
                              hipStream_t stream) {
  const float* x = (const float*)d_in[0];
  // d_in[1] (y) only enters the reference as zeros_like -> unused.
  const float* W = (const float*)d_in[2];
  float* out = (float*)d_out;

  uint64_t* buf0 = (uint64_t*)d_ws;
  uint64_t* buf1 = buf0 + DYN;

  // Invalidate stale tags (0xFFFFFFFF matches no t in 1..512) — needed on the
  // first call and between graph replays (harness does not re-poison d_ws).
  hipMemsetAsync(d_ws, 0xFF, (size_t)2 * DYN * sizeof(uint64_t), stream);

  bm_tag<<<dim3(NBLK), dim3(TPB), 0, stream>>>(x, W, buf0, buf1, out);
}